// Round 2
// baseline (2414.236 us; speedup 1.0000x reference)
//
#include <hip/hip_runtime.h>

// CrossBatchEmbeddingMixer: B=8192, H=4096, GH=1024, TEMP=1
// All heavy matmuls in bf16 MFMA (16x16x32), fp32 accumulate, fused epilogues.
// Workspace budget ~224 MB; B*B score matrix + h1 accumulator live inside d_out.

#define HDIM 4096
#define BATCH 8192
#define GHDIM 1024

typedef unsigned short u16;
typedef short bf16x8 __attribute__((ext_vector_type(8)));
typedef float f32x4 __attribute__((ext_vector_type(4)));

__device__ __forceinline__ u16 f2bf(float f) {
  union { float f; unsigned u; } v; v.f = f;
  unsigned r = v.u + 0x7FFFu + ((v.u >> 16) & 1u);
  return (u16)(r >> 16);
}
__device__ __forceinline__ float bf2f(u16 u) {
  union { unsigned u; float f; } v; v.u = ((unsigned)u) << 16;
  return v.f;
}

// ---------------- cast fp32 -> bf16 (vectorized) ----------------
__global__ void cast_f32_bf16(const float* __restrict__ src, u16* __restrict__ dst, int n4) {
  int i = blockIdx.x * 256 + threadIdx.x;
  if (i < n4) {
    float4 f = ((const float4*)src)[i];
    ushort4 o;
    o.x = f2bf(f.x); o.y = f2bf(f.y); o.z = f2bf(f.z); o.w = f2bf(f.w);
    ((ushort4*)dst)[i] = o;
  }
}

// ---------------- mask canonicalization ----------------
// Detect whether attention_mask buffer is 1-byte bool or int32 (0/1).
// If int32, bytes at offsets %4!=0 within the first BATCH bytes are all zero.
__global__ void detect_mask(const unsigned char* __restrict__ m, int nbytes, int* __restrict__ flag) {
  __shared__ int cnt[256];
  int c = 0;
  for (int i = threadIdx.x; i < nbytes; i += 256)
    if ((i & 3) && m[i]) c++;
  cnt[threadIdx.x] = c;
  __syncthreads();
  for (int s = 128; s > 0; s >>= 1) {
    if ((int)threadIdx.x < s) cnt[threadIdx.x] += cnt[threadIdx.x + s];
    __syncthreads();
  }
  if (threadIdx.x == 0) *flag = cnt[0];
}

__global__ void expand_mask(const void* __restrict__ raw, const int* __restrict__ flag,
                            int* __restrict__ mask, int n) {
  int i = blockIdx.x * 256 + threadIdx.x;
  if (i >= n) return;
  int v;
  if (*flag > 0) v = ((const unsigned char*)raw)[i];   // bool layout
  else           v = ((const int*)raw)[i];             // int32 layout
  mask[i] = (v != 0) ? 1 : 0;
}

// ---------------- row L2-normalize (in place, bf16 [BATCH][HDIM]) ----------------
__global__ void normalize_rows(u16* __restrict__ p) {
  int row = blockIdx.x;
  uint4* r = (uint4*)(p + (size_t)row * HDIM);
  uint4 d[2];
  float s = 0.f;
#pragma unroll
  for (int i = 0; i < 2; i++) {
    d[i] = r[i * 256 + threadIdx.x];
    const u16* u = (const u16*)&d[i];
#pragma unroll
    for (int j = 0; j < 8; j++) { float f = bf2f(u[j]); s += f * f; }
  }
  __shared__ float red[256];
  red[threadIdx.x] = s;
  __syncthreads();
  for (int st = 128; st > 0; st >>= 1) {
    if ((int)threadIdx.x < st) red[threadIdx.x] += red[threadIdx.x + st];
    __syncthreads();
  }
  float scale = 1.0f / fmaxf(sqrtf(red[0]), 1e-12f);
#pragma unroll
  for (int i = 0; i < 2; i++) {
    u16* u = (u16*)&d[i];
#pragma unroll
    for (int j = 0; j < 8; j++) u[j] = f2bf(bf2f(u[j]) * scale);
    r[i * 256 + threadIdx.x] = d[i];
  }
}

// ---------------- row softmax (in place, bf16 [BATCH][BATCH], -inf masked) ----------------
__global__ void softmax_rows(u16* __restrict__ sim) {
  int row = blockIdx.x;
  uint4* r = (uint4*)(sim + (size_t)row * BATCH);
  uint4 d[4];
  float v[32];
  float mx = -3.0e38f;
#pragma unroll
  for (int i = 0; i < 4; i++) {
    d[i] = r[i * 256 + threadIdx.x];
    const u16* u = (const u16*)&d[i];
#pragma unroll
    for (int j = 0; j < 8; j++) {
      float f = bf2f(u[j]);
      v[i * 8 + j] = f;
      mx = fmaxf(mx, f);
    }
  }
  __shared__ float red[256];
  red[threadIdx.x] = mx;
  __syncthreads();
  for (int st = 128; st > 0; st >>= 1) {
    if ((int)threadIdx.x < st) red[threadIdx.x] = fmaxf(red[threadIdx.x], red[threadIdx.x + st]);
    __syncthreads();
  }
  mx = red[0];
  __syncthreads();
  float s = 0.f;
#pragma unroll
  for (int i = 0; i < 32; i++) {
    float e = (v[i] < -1.0e30f) ? 0.f : __expf(v[i] - mx);
    v[i] = e;
    s += e;
  }
  red[threadIdx.x] = s;
  __syncthreads();
  for (int st = 128; st > 0; st >>= 1) {
    if ((int)threadIdx.x < st) red[threadIdx.x] += red[threadIdx.x + st];
    __syncthreads();
  }
  float inv = (red[0] > 0.f) ? 1.0f / red[0] : 0.f;  // nan_to_num: all-masked row -> zeros
#pragma unroll
  for (int i = 0; i < 4; i++) {
    u16* u = (u16*)&d[i];
#pragma unroll
    for (int j = 0; j < 8; j++) u[j] = f2bf(v[i * 8 + j] * inv);
    r[i * 256 + threadIdx.x] = d[i];
  }
}

// ---------------- bf16 MFMA GEMM: C[M][N] = A[M][K] @ B[N][K]^T ----------------
// 128x128 tile, BK=64, 4 waves (2x2), each wave 64x64 via 4x4 mfma_f32_16x16x32_bf16.
// Staging via global_load_lds width=16; XOR swizzle (k8 ^= row&7) to break LDS bank conflicts.
enum { EPI_BF16 = 0, EPI_SIM = 1, EPI_F32 = 2, EPI_GELU = 3, EPI_FINAL = 4 };

__device__ __forceinline__ void async_load16(const u16* g, u16* l) {
  __builtin_amdgcn_global_load_lds(
      (const __attribute__((address_space(1))) void*)g,
      (__attribute__((address_space(3))) void*)l, 16, 0, 0);
}

template <int EPI>
__global__ __launch_bounds__(256) void gemm_bt(
    const u16* __restrict__ A, int lda,
    const u16* __restrict__ B, int ldb,
    void* __restrict__ C, int ldc,
    int M, int N, int K,
    const int* __restrict__ mask,      // EPI_SIM
    const float* __restrict__ aux,     // EPI_GELU: h1acc fp32 | EPI_FINAL: hidden fp32
    const u16* __restrict__ aux2,      // EPI_FINAL: cross bf16
    const float* __restrict__ bias) {  // EPI_GELU: b_g1 | EPI_FINAL: b_g2
  __shared__ __align__(16) u16 lA[128 * 64];
  __shared__ __align__(16) u16 lB[128 * 64];
  const int tid = threadIdx.x;
  const int lane = tid & 63;
  const int wave = tid >> 6;
  const int waveRow = (wave >> 1) * 64;
  const int waveCol = (wave & 1) * 64;
  const int rowBase = blockIdx.y * 128;
  const int colBase = blockIdx.x * 128;

  const u16* Ab = A + (size_t)rowBase * lda;
  const u16* Bb = B + (size_t)colBase * ldb;

  f32x4 zero = {0.f, 0.f, 0.f, 0.f};
  f32x4 acc[4][4];
#pragma unroll
  for (int mi = 0; mi < 4; mi++)
#pragma unroll
    for (int ni = 0; ni < 4; ni++) acc[mi][ni] = zero;

  for (int kt = 0; kt < K; kt += 64) {
#pragma unroll
    for (int i = 0; i < 4; i++) {
      int c = i * 256 + tid;            // chunk of 8 bf16
      int row = c >> 3, k8 = c & 7;
      int gk8 = k8 ^ (row & 7);         // LDS chunk (row,k8) holds global (row, k8^row&7)
      async_load16(Ab + (size_t)row * lda + kt + gk8 * 8, &lA[c * 8]);
    }
#pragma unroll
    for (int i = 0; i < 4; i++) {
      int c = i * 256 + tid;
      int row = c >> 3, k8 = c & 7;
      int gk8 = k8 ^ (row & 7);
      async_load16(Bb + (size_t)row * ldb + kt + gk8 * 8, &lB[c * 8]);
    }
    __syncthreads();
#pragma unroll
    for (int ks = 0; ks < 2; ks++) {
      const int kq = ks * 4 + (lane >> 4);  // k8 index this lane-quad reads
      bf16x8 af[4], bfr[4];
#pragma unroll
      for (int mi = 0; mi < 4; mi++) {
        int row = waveRow + mi * 16 + (lane & 15);
        af[mi] = *(const bf16x8*)&lA[row * 64 + ((kq ^ (row & 7)) * 8)];
      }
#pragma unroll
      for (int ni = 0; ni < 4; ni++) {
        int row = waveCol + ni * 16 + (lane & 15);
        bfr[ni] = *(const bf16x8*)&lB[row * 64 + ((kq ^ (row & 7)) * 8)];
      }
#pragma unroll
      for (int mi = 0; mi < 4; mi++)
#pragma unroll
        for (int ni = 0; ni < 4; ni++)
          acc[mi][ni] = __builtin_amdgcn_mfma_f32_16x16x32_bf16(af[mi], bfr[ni], acc[mi][ni], 0, 0, 0);
    }
    __syncthreads();
  }

  // Epilogue. C/D layout: col = lane&15, row = (lane>>4)*4 + reg  [m89-verified]
  const int quad = lane >> 4, lcol = lane & 15;
#pragma unroll
  for (int mi = 0; mi < 4; mi++) {
#pragma unroll
    for (int ni = 0; ni < 4; ni++) {
#pragma unroll
      for (int r = 0; r < 4; r++) {
        int grow = rowBase + waveRow + mi * 16 + quad * 4 + r;
        int gcol = colBase + waveCol + ni * 16 + lcol;
        float v = acc[mi][ni][r];
        size_t idx = (size_t)grow * ldc + gcol;
        if constexpr (EPI == EPI_BF16) {
          ((u16*)C)[idx] = f2bf(v);
        } else if constexpr (EPI == EPI_SIM) {
          bool dead = (grow == gcol) || (mask[gcol] == 0);
          ((u16*)C)[idx] = dead ? (u16)0xFF80 : f2bf(v);  // 0xFF80 = -inf bf16
        } else if constexpr (EPI == EPI_F32) {
          ((float*)C)[idx] = v;
        } else if constexpr (EPI == EPI_GELU) {
          float x = v + aux[idx] + bias[gcol];
          float g = 0.5f * x * (1.0f + erff(x * 0.70710678118654752f));  // exact GELU
          ((u16*)C)[idx] = f2bf(g);
        } else {  // EPI_FINAL: out = hidden + sigmoid(acc + b2) * cross
          float x = v + bias[gcol];
          float g = 1.0f / (1.0f + __expf(-x));
          ((float*)C)[idx] = aux[idx] + g * bf2f(aux2[idx]);
        }
      }
    }
  }
}

// ---------------- host launch ----------------
extern "C" void kernel_launch(void* const* d_in, const int* in_sizes, int n_in,
                              void* d_out, int out_size, void* d_ws, size_t ws_size,
                              hipStream_t stream) {
  const float* hs   = (const float*)d_in[0];
  const void*  mraw = d_in[1];
  const float* Wsim = (const float*)d_in[2];
  const float* Wval = (const float*)d_in[3];
  const float* Wg1  = (const float*)d_in[4];
  const float* bg1  = (const float*)d_in[5];
  const float* Wg2  = (const float*)d_in[6];
  const float* bg2  = (const float*)d_in[7];
  float* out = (float*)d_out;

  // ---- workspace layout (~224 MB), liveness-aliased ----
  char* ws = (char*)d_ws;
  size_t off = 0;
  auto alloc = [&](size_t bytes) {
    char* p = ws + off;
    off += (bytes + 255) & ~(size_t)255;
    return p;
  };
  u16* hidden_bf = (u16*)alloc((size_t)BATCH * HDIM * 2);  // 67 MB, live whole time
  u16* wbuf      = (u16*)alloc((size_t)HDIM * HDIM * 2);   // 33.5 MB, Wsim->Wval->Wg1->Wg2
  u16* r1        = (u16*)alloc((size_t)BATCH * HDIM * 2);  // 67 MB: proj/normed -> valuesT -> h1_bf
  u16* cross_bf  = (u16*)alloc((size_t)BATCH * HDIM * 2);  // 67 MB
  int* mask_i    = (int*)alloc((size_t)BATCH * 4);
  int* flag      = (int*)alloc(256);
  if (off > ws_size) return;  // ws too small -> clean absmax failure, not a GPU fault

  // d_out overlays (134 MB): simw (bf16 B*B, exactly out bytes), then h1acc (fp32)
  u16*   simw  = (u16*)d_out;
  float* h1acc = (float*)d_out;

  u16* normed  = r1;
  u16* valuesT = r1;   // after normed dies (post sim-GEMM)
  u16* h1_bf   = r1;   // after valuesT dies (post cross-GEMM)
  (void)in_sizes; (void)n_in; (void)out_size;

  // mask canonicalization (handles bool-byte or int32 delivery)
  detect_mask<<<1, 256, 0, stream>>>((const unsigned char*)mraw, BATCH, flag);
  expand_mask<<<BATCH / 256, 256, 0, stream>>>(mraw, flag, mask_i, BATCH);

  dim3 blk(256);

  // hidden -> bf16
  cast_f32_bf16<<<(BATCH * HDIM / 4) / 256, 256, 0, stream>>>(hs, hidden_bf, BATCH * HDIM / 4);

  // proj = hidden @ Wsim^T   [BATCH, HDIM] -> r1
  cast_f32_bf16<<<(HDIM * HDIM / 4) / 256, 256, 0, stream>>>(Wsim, wbuf, HDIM * HDIM / 4);
  gemm_bt<EPI_BF16><<<dim3(HDIM / 128, BATCH / 128), blk, 0, stream>>>(
      hidden_bf, HDIM, wbuf, HDIM, normed, HDIM, BATCH, HDIM, HDIM,
      nullptr, nullptr, nullptr, nullptr);
  // L2 normalize rows in place
  normalize_rows<<<BATCH, 256, 0, stream>>>(normed);

  // sim = normed @ normed^T with mask epilogue  [BATCH, BATCH] -> simw (d_out)
  gemm_bt<EPI_SIM><<<dim3(BATCH / 128, BATCH / 128), blk, 0, stream>>>(
      normed, HDIM, normed, HDIM, simw, BATCH, BATCH, BATCH, HDIM,
      mask_i, nullptr, nullptr, nullptr);
  // softmax rows (in place) -> weights
  softmax_rows<<<BATCH, 256, 0, stream>>>(simw);

  // valuesT = Wval @ hidden^T  [HDIM, BATCH] -> r1 (normed dead)
  cast_f32_bf16<<<(HDIM * HDIM / 4) / 256, 256, 0, stream>>>(Wval, wbuf, HDIM * HDIM / 4);
  gemm_bt<EPI_BF16><<<dim3(BATCH / 128, HDIM / 128), blk, 0, stream>>>(
      wbuf, HDIM, hidden_bf, HDIM, valuesT, BATCH, HDIM, BATCH, HDIM,
      nullptr, nullptr, nullptr, nullptr);

  // cross = weights @ valuesT^T  [BATCH, HDIM] -> cross_bf
  gemm_bt<EPI_BF16><<<dim3(HDIM / 128, BATCH / 128), blk, 0, stream>>>(
      simw, BATCH, valuesT, BATCH, cross_bf, HDIM, BATCH, HDIM, BATCH,
      nullptr, nullptr, nullptr, nullptr);

  // h1 pass 1: hidden @ Wg1[:, :H]^T -> fp32 acc (d_out; simw dead)  [BATCH, GHDIM]
  cast_f32_bf16<<<(GHDIM * 2 * HDIM / 4) / 256, 256, 0, stream>>>(Wg1, wbuf, GHDIM * 2 * HDIM / 4);
  gemm_bt<EPI_F32><<<dim3(GHDIM / 128, BATCH / 128), blk, 0, stream>>>(
      hidden_bf, HDIM, wbuf, 2 * HDIM, h1acc, GHDIM, BATCH, GHDIM, HDIM,
      nullptr, nullptr, nullptr, nullptr);
  // h1 pass 2: + cross @ Wg1[:, H:]^T, + b_g1, exact GELU -> h1_bf (r1; valuesT dead)
  gemm_bt<EPI_GELU><<<dim3(GHDIM / 128, BATCH / 128), blk, 0, stream>>>(
      cross_bf, HDIM, wbuf + HDIM, 2 * HDIM, h1_bf, GHDIM, BATCH, GHDIM, HDIM,
      nullptr, h1acc, nullptr, bg1);

  // out = hidden + sigmoid(h1 @ Wg2^T + b_g2) * cross   [BATCH, HDIM] fp32 -> d_out
  cast_f32_bf16<<<(HDIM * GHDIM / 4) / 256, 256, 0, stream>>>(Wg2, wbuf, HDIM * GHDIM / 4);
  gemm_bt<EPI_FINAL><<<dim3(HDIM / 128, BATCH / 128), blk, 0, stream>>>(
      h1_bf, GHDIM, wbuf, GHDIM, out, HDIM, BATCH, HDIM, GHDIM,
      nullptr, hs, cross_bf, bg2);
}

// Round 3
// 2011.361 us; speedup vs baseline: 1.2003x; 1.2003x over previous
//
#include <hip/hip_runtime.h>

// CrossBatchEmbeddingMixer: B=8192, H=4096, GH=1024, TEMP=1
// bf16 MFMA GEMMs (16x16x32), fp32 accumulate, fused epilogues.
// Mask compaction: ~50% of columns are masked -> softmax weight exactly 0 ->
// sim/valuesT/cross computed only over the Kc valid columns (device-side count,
// static grids with early-exit so graph capture stays valid).
// ws footprint ~235 MB; B*B score matrix + h1 accumulator live inside d_out.

#define HDIM 4096
#define BATCH 8192
#define GHDIM 1024

typedef unsigned short u16;
typedef short bf16x8 __attribute__((ext_vector_type(8)));
typedef float f32x4 __attribute__((ext_vector_type(4)));

__device__ __forceinline__ u16 f2bf(float f) {
  union { float f; unsigned u; } v; v.f = f;
  unsigned r = v.u + 0x7FFFu + ((v.u >> 16) & 1u);
  return (u16)(r >> 16);
}
__device__ __forceinline__ float bf2f(u16 u) {
  union { unsigned u; float f; } v; v.u = ((unsigned)u) << 16;
  return v.f;
}

// ---------------- cast fp32 -> bf16 (vectorized) ----------------
__global__ void cast_f32_bf16(const float* __restrict__ src, u16* __restrict__ dst, int n4) {
  int i = blockIdx.x * 256 + threadIdx.x;
  if (i < n4) {
    float4 f = ((const float4*)src)[i];
    ushort4 o;
    o.x = f2bf(f.x); o.y = f2bf(f.y); o.z = f2bf(f.z); o.w = f2bf(f.w);
    ((ushort4*)dst)[i] = o;
  }
}

// ---------------- mask canonicalization ----------------
// Detect whether attention_mask buffer is 1-byte bool or int32 (0/1):
// if int32, bytes at offsets %4!=0 within the first BATCH bytes are all zero.
__global__ void detect_mask(const unsigned char* __restrict__ m, int nbytes, int* __restrict__ flag) {
  __shared__ int cnt[256];
  int c = 0;
  for (int i = threadIdx.x; i < nbytes; i += 256)
    if ((i & 3) && m[i]) c++;
  cnt[threadIdx.x] = c;
  __syncthreads();
  for (int s = 128; s > 0; s >>= 1) {
    if ((int)threadIdx.x < s) cnt[threadIdx.x] += cnt[threadIdx.x + s];
    __syncthreads();
  }
  if (threadIdx.x == 0) *flag = cnt[0];
}

// ---------------- compact valid column indices ----------------
// idxc[0..kc) = ascending original indices of valid samples; idxc[kc..B)=-1.
// kinfo[0]=kc, kinfo[1]=kc rounded up to 128 (tile-aligned).
__global__ void compact_mask(const void* __restrict__ raw, const int* __restrict__ flag,
                             int* __restrict__ idxc, int* __restrict__ kinfo) {
  const int t = threadIdx.x;
  const bool isbool = (*flag > 0);
  __shared__ int cnt[256];
  __shared__ int total;
  const int base0 = t * 32;
  int c = 0;
  for (int i = 0; i < 32; i++) {
    int gi = base0 + i;
    int v = isbool ? ((const unsigned char*)raw)[gi] : ((const int*)raw)[gi];
    if (v) c++;
  }
  cnt[t] = c;
  __syncthreads();
  if (t == 0) {
    int acc = 0;
    for (int i = 0; i < 256; i++) { int x = cnt[i]; cnt[i] = acc; acc += x; }
    total = acc;
    kinfo[0] = acc;
    kinfo[1] = (acc + 127) & ~127;
  }
  __syncthreads();
  int w = cnt[t];
  for (int i = 0; i < 32; i++) {
    int gi = base0 + i;
    int v = isbool ? ((const unsigned char*)raw)[gi] : ((const int*)raw)[gi];
    if (v) idxc[w++] = gi;
  }
  for (int i = total + t; i < BATCH; i += 256) idxc[i] = -1;
}

// ---------------- gather valid rows [kc_pad, H], zero-fill pad rows ----------------
__global__ void gather_rows(const u16* __restrict__ src, u16* __restrict__ dst,
                            const int* __restrict__ idxc, const int* __restrict__ kinfo) {
  int c = blockIdx.x;
  int kc = kinfo[0], kp = kinfo[1];
  if (c >= kp) return;
  uint4* d = (uint4*)(dst + (size_t)c * HDIM);
  if (c < kc) {
    const uint4* s = (const uint4*)(src + (size_t)idxc[c] * HDIM);
    d[threadIdx.x] = s[threadIdx.x];
    d[threadIdx.x + 256] = s[threadIdx.x + 256];
  } else {
    uint4 z = {0, 0, 0, 0};
    d[threadIdx.x] = z;
    d[threadIdx.x + 256] = z;
  }
}

// ---------------- row L2-normalize (in place, bf16 [BATCH][HDIM]) ----------------
__global__ void normalize_rows(u16* __restrict__ p) {
  int row = blockIdx.x;
  uint4* r = (uint4*)(p + (size_t)row * HDIM);
  uint4 d[2];
  float s = 0.f;
#pragma unroll
  for (int i = 0; i < 2; i++) {
    d[i] = r[i * 256 + threadIdx.x];
    const u16* u = (const u16*)&d[i];
#pragma unroll
    for (int j = 0; j < 8; j++) { float f = bf2f(u[j]); s += f * f; }
  }
  __shared__ float red[256];
  red[threadIdx.x] = s;
  __syncthreads();
  for (int st = 128; st > 0; st >>= 1) {
    if ((int)threadIdx.x < st) red[threadIdx.x] += red[threadIdx.x + st];
    __syncthreads();
  }
  float scale = 1.0f / fmaxf(sqrtf(red[0]), 1e-12f);
#pragma unroll
  for (int i = 0; i < 2; i++) {
    u16* u = (u16*)&d[i];
#pragma unroll
    for (int j = 0; j < 8; j++) u[j] = f2bf(bf2f(u[j]) * scale);
    r[i * 256 + threadIdx.x] = d[i];
  }
}

// ---------------- row softmax over kc_pad compacted cols (in place, ld=BATCH) ----------------
__global__ void softmax_rows_dyn(u16* __restrict__ sim, const int* __restrict__ kinfo) {
  const int kp = kinfo[1];
  const int row = blockIdx.x;
  uint4* r = (uint4*)(sim + (size_t)row * BATCH);
  float v[32];
  int active[4];
  float mx = -3.0e38f;
#pragma unroll
  for (int ch = 0; ch < 4; ch++) {
    int base = ch * 2048 + threadIdx.x * 8;
    active[ch] = (base < kp);
    if (active[ch]) {
      uint4 d = r[ch * 256 + threadIdx.x];
      const u16* u = (const u16*)&d;
#pragma unroll
      for (int j = 0; j < 8; j++) {
        float f = bf2f(u[j]);
        v[ch * 8 + j] = f;
        mx = fmaxf(mx, f);
      }
    }
  }
  __shared__ float red[256];
  red[threadIdx.x] = mx;
  __syncthreads();
  for (int st = 128; st > 0; st >>= 1) {
    if ((int)threadIdx.x < st) red[threadIdx.x] = fmaxf(red[threadIdx.x], red[threadIdx.x + st]);
    __syncthreads();
  }
  mx = red[0];
  __syncthreads();
  float s = 0.f;
#pragma unroll
  for (int ch = 0; ch < 4; ch++) {
    if (active[ch]) {
#pragma unroll
      for (int j = 0; j < 8; j++) {
        float e = (v[ch * 8 + j] < -1.0e30f) ? 0.f : __expf(v[ch * 8 + j] - mx);
        v[ch * 8 + j] = e;
        s += e;
      }
    }
  }
  red[threadIdx.x] = s;
  __syncthreads();
  for (int st = 128; st > 0; st >>= 1) {
    if ((int)threadIdx.x < st) red[threadIdx.x] += red[threadIdx.x + st];
    __syncthreads();
  }
  float inv = (red[0] > 0.f) ? 1.0f / red[0] : 0.f;  // nan_to_num: all-masked row -> zeros
#pragma unroll
  for (int ch = 0; ch < 4; ch++) {
    if (active[ch]) {
      uint4 d;
      u16* u = (u16*)&d;
#pragma unroll
      for (int j = 0; j < 8; j++) u[j] = f2bf(v[ch * 8 + j] * inv);
      r[ch * 256 + threadIdx.x] = d;
    }
  }
}

// ---------------- bf16 MFMA GEMM: C[M][N] = A[M][K] @ B[N][K]^T ----------------
// 128x128 tile, BK=64, 4 waves (2x2), each wave 64x64 via 4x4 mfma_f32_16x16x32_bf16.
// Staging via global_load_lds width=16; XOR swizzle (k8 ^= row&7) breaks LDS bank conflicts.
// dynN: exit blocks whose colBase >= kinfo[1]. dynK: K-loop bound = kinfo[1].
enum { EPI_BF16 = 0, EPI_SIM = 1, EPI_F32 = 2, EPI_GELU = 3, EPI_FINAL = 4 };

__device__ __forceinline__ void async_load16(const u16* g, u16* l) {
  __builtin_amdgcn_global_load_lds(
      (const __attribute__((address_space(1))) void*)g,
      (__attribute__((address_space(3))) void*)l, 16, 0, 0);
}

template <int EPI>
__global__ __launch_bounds__(256) void gemm_bt(
    const u16* __restrict__ A, int lda,
    const u16* __restrict__ B, int ldb,
    void* __restrict__ C, int ldc,
    int M, int N, int K,
    const int* __restrict__ kinfo, int dynN, int dynK,
    const int* __restrict__ idxc,      // EPI_SIM: original index per compacted col
    const float* __restrict__ aux,     // EPI_GELU: h1acc fp32 | EPI_FINAL: hidden fp32
    const u16* __restrict__ aux2,      // EPI_FINAL: cross bf16
    const float* __restrict__ bias) {  // EPI_GELU: b_g1 | EPI_FINAL: b_g2
  const int rowBase = blockIdx.y * 128;
  const int colBase = blockIdx.x * 128;
  if (dynN && colBase >= kinfo[1]) return;
  const int Keff = dynK ? kinfo[1] : K;

  __shared__ __align__(16) u16 lA[128 * 64];
  __shared__ __align__(16) u16 lB[128 * 64];
  const int tid = threadIdx.x;
  const int lane = tid & 63;
  const int wave = tid >> 6;
  const int waveRow = (wave >> 1) * 64;
  const int waveCol = (wave & 1) * 64;

  const u16* Ab = A + (size_t)rowBase * lda;
  const u16* Bb = B + (size_t)colBase * ldb;

  f32x4 zero = {0.f, 0.f, 0.f, 0.f};
  f32x4 acc[4][4];
#pragma unroll
  for (int mi = 0; mi < 4; mi++)
#pragma unroll
    for (int ni = 0; ni < 4; ni++) acc[mi][ni] = zero;

  for (int kt = 0; kt < Keff; kt += 64) {
#pragma unroll
    for (int i = 0; i < 4; i++) {
      int c = i * 256 + tid;            // chunk of 8 bf16
      int row = c >> 3, k8 = c & 7;
      int gk8 = k8 ^ (row & 7);         // LDS chunk (row,k8) holds global (row, k8^row&7)
      async_load16(Ab + (size_t)row * lda + kt + gk8 * 8, &lA[c * 8]);
    }
#pragma unroll
    for (int i = 0; i < 4; i++) {
      int c = i * 256 + tid;
      int row = c >> 3, k8 = c & 7;
      int gk8 = k8 ^ (row & 7);
      async_load16(Bb + (size_t)row * ldb + kt + gk8 * 8, &lB[c * 8]);
    }
    __syncthreads();
#pragma unroll
    for (int ks = 0; ks < 2; ks++) {
      const int kq = ks * 4 + (lane >> 4);  // k8 index this lane-quad reads
      bf16x8 af[4], bfr[4];
#pragma unroll
      for (int mi = 0; mi < 4; mi++) {
        int row = waveRow + mi * 16 + (lane & 15);
        af[mi] = *(const bf16x8*)&lA[row * 64 + ((kq ^ (row & 7)) * 8)];
      }
#pragma unroll
      for (int ni = 0; ni < 4; ni++) {
        int row = waveCol + ni * 16 + (lane & 15);
        bfr[ni] = *(const bf16x8*)&lB[row * 64 + ((kq ^ (row & 7)) * 8)];
      }
#pragma unroll
      for (int mi = 0; mi < 4; mi++)
#pragma unroll
        for (int ni = 0; ni < 4; ni++)
          acc[mi][ni] = __builtin_amdgcn_mfma_f32_16x16x32_bf16(af[mi], bfr[ni], acc[mi][ni], 0, 0, 0);
    }
    __syncthreads();
  }

  // Epilogue. C/D layout: col = lane&15, row = (lane>>4)*4 + reg  [m89-verified]
  const int quad = lane >> 4, lcol = lane & 15;
#pragma unroll
  for (int mi = 0; mi < 4; mi++) {
#pragma unroll
    for (int ni = 0; ni < 4; ni++) {
#pragma unroll
      for (int r = 0; r < 4; r++) {
        int grow = rowBase + waveRow + mi * 16 + quad * 4 + r;
        int gcol = colBase + waveCol + ni * 16 + lcol;
        float v = acc[mi][ni][r];
        size_t idx = (size_t)grow * ldc + gcol;
        if constexpr (EPI == EPI_BF16) {
          ((u16*)C)[idx] = f2bf(v);
        } else if constexpr (EPI == EPI_SIM) {
          bool dead = (gcol >= kinfo[0]) || (idxc[gcol] == grow);
          ((u16*)C)[idx] = dead ? (u16)0xFF80 : f2bf(v);  // 0xFF80 = -inf bf16
        } else if constexpr (EPI == EPI_F32) {
          ((float*)C)[idx] = v;
        } else if constexpr (EPI == EPI_GELU) {
          float x = v + aux[idx] + bias[gcol];
          float g = 0.5f * x * (1.0f + erff(x * 0.70710678118654752f));  // exact GELU
          ((u16*)C)[idx] = f2bf(g);
        } else {  // EPI_FINAL: out = hidden + sigmoid(acc + b2) * cross
          float x = v + bias[gcol];
          float g = 1.0f / (1.0f + __expf(-x));
          ((float*)C)[idx] = aux[idx] + g * bf2f(aux2[idx]);
        }
      }
    }
  }
}

// ---------------- host launch ----------------
extern "C" void kernel_launch(void* const* d_in, const int* in_sizes, int n_in,
                              void* d_out, int out_size, void* d_ws, size_t ws_size,
                              hipStream_t stream) {
  const float* hs   = (const float*)d_in[0];
  const void*  mraw = d_in[1];
  const float* Wsim = (const float*)d_in[2];
  const float* Wval = (const float*)d_in[3];
  const float* Wg1  = (const float*)d_in[4];
  const float* bg1  = (const float*)d_in[5];
  const float* Wg2  = (const float*)d_in[6];
  const float* bg2  = (const float*)d_in[7];
  float* out = (float*)d_out;

  // ---- workspace layout (~235 MB), liveness-aliased ----
  char* ws = (char*)d_ws;
  size_t off = 0;
  auto alloc = [&](size_t bytes) {
    char* p = ws + off;
    off += (bytes + 255) & ~(size_t)255;
    return p;
  };
  u16* hidden_bf = (u16*)alloc((size_t)BATCH * HDIM * 2);  // 67 MB, live whole time
  u16* wbuf      = (u16*)alloc((size_t)HDIM * HDIM * 2);   // 33.5 MB, Wsim->Wval->Wg1->Wg2
  u16* r1        = (u16*)alloc((size_t)BATCH * HDIM * 2);  // 67 MB: normed -> hidden_c -> cross
  u16* r2        = (u16*)alloc((size_t)BATCH * HDIM * 2);  // 67 MB: normed_c -> valuesT_c -> h1_bf
  int* idxc      = (int*)alloc((size_t)BATCH * 4);
  int* kinfo     = (int*)alloc(256);
  int* flag      = (int*)alloc(256);
  if (off > ws_size) return;  // ws too small -> clean absmax failure, not a GPU fault

  // d_out overlays (134 MB): simw (bf16 [B][B], ld=BATCH), later h1acc (fp32 [B][GH])
  u16*   simw  = (u16*)d_out;
  float* h1acc = (float*)d_out;
  (void)in_sizes; (void)n_in; (void)out_size;

  dim3 blk(256);

  // mask canonicalization + compaction
  detect_mask<<<1, 256, 0, stream>>>((const unsigned char*)mraw, BATCH, flag);
  compact_mask<<<1, 256, 0, stream>>>(mraw, flag, idxc, kinfo);

  // hidden -> bf16
  cast_f32_bf16<<<(BATCH * HDIM / 4) / 256, 256, 0, stream>>>(hs, hidden_bf, BATCH * HDIM / 4);

  // proj = hidden @ Wsim^T  [B, H] -> r1 (normed)
  cast_f32_bf16<<<(HDIM * HDIM / 4) / 256, 256, 0, stream>>>(Wsim, wbuf, HDIM * HDIM / 4);
  gemm_bt<EPI_BF16><<<dim3(HDIM / 128, BATCH / 128), blk, 0, stream>>>(
      hidden_bf, HDIM, wbuf, HDIM, r1, HDIM, BATCH, HDIM, HDIM,
      nullptr, 0, 0, nullptr, nullptr, nullptr, nullptr);
  normalize_rows<<<BATCH, 256, 0, stream>>>(r1);

  // gather valid normed rows -> r2 (normed_c [kc_pad, H])
  gather_rows<<<BATCH, 256, 0, stream>>>(r1, r2, idxc, kinfo);

  // sim = normed @ normed_c^T  [B, kc_pad] (ld=BATCH) -> simw, fused self/-pad mask
  gemm_bt<EPI_SIM><<<dim3(BATCH / 128, BATCH / 128), blk, 0, stream>>>(
      r1, HDIM, r2, HDIM, simw, BATCH, BATCH, BATCH, HDIM,
      kinfo, 1, 0, idxc, nullptr, nullptr, nullptr);
  softmax_rows_dyn<<<BATCH, 256, 0, stream>>>(simw, kinfo);

  // gather valid hidden rows -> r1 (hidden_c; normed dead)
  gather_rows<<<BATCH, 256, 0, stream>>>(hidden_bf, r1, idxc, kinfo);

  // valuesT_c = Wval @ hidden_c^T  [H, kc_pad] (ld=BATCH) -> r2 (normed_c dead)
  cast_f32_bf16<<<(HDIM * HDIM / 4) / 256, 256, 0, stream>>>(Wval, wbuf, HDIM * HDIM / 4);
  gemm_bt<EPI_BF16><<<dim3(BATCH / 128, HDIM / 128), blk, 0, stream>>>(
      wbuf, HDIM, r1, HDIM, r2, BATCH, HDIM, BATCH, HDIM,
      kinfo, 1, 0, nullptr, nullptr, nullptr, nullptr);

  // cross = weights_c @ valuesT_c^T  [B, H], K = kc_pad -> r1 (hidden_c dead)
  gemm_bt<EPI_BF16><<<dim3(HDIM / 128, BATCH / 128), blk, 0, stream>>>(
      simw, BATCH, r2, BATCH, r1, HDIM, BATCH, HDIM, BATCH,
      kinfo, 0, 1, nullptr, nullptr, nullptr, nullptr);

  // h1 pass 1: hidden @ Wg1[:, :H]^T -> fp32 acc (d_out; simw dead)  [B, GH]
  cast_f32_bf16<<<(GHDIM * 2 * HDIM / 4) / 256, 256, 0, stream>>>(Wg1, wbuf, GHDIM * 2 * HDIM / 4);
  gemm_bt<EPI_F32><<<dim3(GHDIM / 128, BATCH / 128), blk, 0, stream>>>(
      hidden_bf, HDIM, wbuf, 2 * HDIM, h1acc, GHDIM, BATCH, GHDIM, HDIM,
      nullptr, 0, 0, nullptr, nullptr, nullptr, nullptr);
  // h1 pass 2: + cross @ Wg1[:, H:]^T, + b_g1, exact GELU -> r2 (h1_bf; valuesT dead)
  gemm_bt<EPI_GELU><<<dim3(GHDIM / 128, BATCH / 128), blk, 0, stream>>>(
      r1, HDIM, wbuf + HDIM, 2 * HDIM, r2, GHDIM, BATCH, GHDIM, HDIM,
      nullptr, 0, 0, nullptr, h1acc, nullptr, bg1);

  // out = hidden + sigmoid(h1 @ Wg2^T + b_g2) * cross  [B, H] fp32 -> d_out
  cast_f32_bf16<<<(HDIM * GHDIM / 4) / 256, 256, 0, stream>>>(Wg2, wbuf, HDIM * GHDIM / 4);
  gemm_bt<EPI_FINAL><<<dim3(HDIM / 128, BATCH / 128), blk, 0, stream>>>(
      r2, GHDIM, wbuf, GHDIM, out, HDIM, BATCH, HDIM, GHDIM,
      nullptr, 0, 0, nullptr, hs, r1, bg2);
}